// Round 1
// baseline (513.699 us; speedup 1.0000x reference)
//
#include <hip/hip_runtime.h>
#include <hip/hip_bf16.h>

typedef __attribute__((ext_vector_type(8))) short short8;
typedef __attribute__((ext_vector_type(4))) float f32x4;
typedef unsigned short u16;
typedef unsigned int u32;

#define NORM_INV (1.0f / 100.0f)

__device__ __forceinline__ float silu(float x) {
    return x / (1.0f + __expf(-x));
}

__device__ __forceinline__ u16 f2bf(float x) {
    union { float f; u32 u; } v; v.f = x;
    u32 r = v.u + 0x7fff + ((v.u >> 16) & 1);   // RNE
    return (u16)(r >> 16);
}

__device__ __forceinline__ float bf2f(u16 b) {
    union { u32 u; float f; } v; v.u = ((u32)b) << 16;
    return v.f;
}

// ---------------- kernel 0: weight transposes (tiny) ----------------
__global__ void prep_weights(const float* __restrict__ W1, const float* __restrict__ W2,
                             u16* __restrict__ W1abT, u16* __restrict__ W2T) {
    int idx = blockIdx.x * blockDim.x + threadIdx.x;
    if (idx < 256 * 128) {
        int j = idx >> 7, k = idx & 127;
        float v = (j < 128) ? W1[k * 128 + j] : W1[(128 + k) * 128 + (j - 128)];
        W1abT[j * 128 + k] = f2bf(v);
    } else if (idx < 256 * 128 + 128 * 128) {
        int t = idx - 256 * 128;
        int n = t >> 7, k = t & 127;
        W2T[n * 128 + k] = f2bf(W2[k * 128 + n]);
    }
}

// ---------------- kernel 1: AB[node][256] = [h@W1a + b1 | h@W1b] ----------------
__global__ __launch_bounds__(256) void ab_kernel(const float* __restrict__ h,
        const float* __restrict__ b1, const u16* __restrict__ W1abT,
        u16* __restrict__ AB, int N) {
    __shared__ u16 hs[32 * 128];     // 32 nodes x 128 k, bf16, XOR-swizzled
    int tid = threadIdx.x;
    int n0 = blockIdx.x * 32;
    int lane = tid & 63, wave = tid >> 6;

    // stage h tile -> bf16 LDS (swizzle: byte ^= (row&7)<<4)
    #pragma unroll
    for (int it = 0; it < 8; ++it) {
        int item = it * 256 + tid;          // 2048 items, 2 k each
        int m = item >> 6;
        int k = (item & 63) * 2;
        float2 hv = make_float2(0.f, 0.f);
        if (n0 + m < N) hv = *(const float2*)(h + (size_t)(n0 + m) * 128 + k);
        u32 pk = (u32)f2bf(hv.x) | ((u32)f2bf(hv.y) << 16);
        int byteoff = m * 256 + ((k * 2) ^ ((m & 7) << 4));
        *(u32*)((char*)hs + byteoff) = pk;
    }

    // W1abT B-fragments, held in registers: wave covers cols wave*64 .. +63
    short8 bw[4][4];
    #pragma unroll
    for (int nt = 0; nt < 4; ++nt) {
        int j = wave * 64 + nt * 16 + (lane & 15);
        #pragma unroll
        for (int ks = 0; ks < 4; ++ks)
            bw[nt][ks] = *(const short8*)((const char*)W1abT + j * 256 + ks * 64 + (lane >> 4) * 16);
    }
    __syncthreads();

    f32x4 acc[2][4] = {};
    #pragma unroll
    for (int ks = 0; ks < 4; ++ks) {
        short8 a[2];
        #pragma unroll
        for (int mt = 0; mt < 2; ++mt) {
            int row = mt * 16 + (lane & 15);
            int byteoff = row * 256 + (((ks * 64) + ((lane >> 4) * 16)) ^ ((row & 7) << 4));
            a[mt] = *(short8*)((char*)hs + byteoff);
        }
        #pragma unroll
        for (int mt = 0; mt < 2; ++mt)
            #pragma unroll
            for (int nt = 0; nt < 4; ++nt)
                acc[mt][nt] = __builtin_amdgcn_mfma_f32_16x16x32_bf16(a[mt], bw[nt][ks], acc[mt][nt], 0, 0, 0);
    }

    // epilogue: + b1 on A-half, store bf16
    #pragma unroll
    for (int mt = 0; mt < 2; ++mt) {
        #pragma unroll
        for (int nt = 0; nt < 4; ++nt) {
            int j = wave * 64 + nt * 16 + (lane & 15);
            float bias = (j < 128) ? b1[j] : 0.f;
            #pragma unroll
            for (int r = 0; r < 4; ++r) {
                int node = n0 + mt * 16 + (lane >> 4) * 4 + r;
                if (node < N) AB[(size_t)node * 256 + j] = f2bf(acc[mt][nt][r] + bias);
            }
        }
    }
}

// ---------------- kernel 2: per-edge MLP + scatter ----------------
__global__ __launch_bounds__(256) void edge_kernel(
        const u16* __restrict__ AB, const u16* __restrict__ W2T,
        const int* __restrict__ eidx, const float* __restrict__ coord_diff,
        const float* __restrict__ edge_attr, const float* __restrict__ edge_mask,
        const float* __restrict__ W1, const float* __restrict__ b2,
        const float* __restrict__ W3, float* __restrict__ agg, int E) {
    __shared__ u16 x1s[32 * 128];    // 32 edges x 128 ch, bf16, swizzled
    __shared__ float sp[4][32];
    __shared__ int srow[32];
    __shared__ float scd[32][3];

    int tid = threadIdx.x;
    int lane = tid & 63, wave = tid >> 6;
    int ch = tid & 127, esub = tid >> 7;
    float w1c = W1[256 * 128 + ch];            // last row of W1 (edge_attr weights)

    // W2 B-fragments in registers: wave covers out cols wave*32 .. +31
    short8 bw[2][4];
    float b2v[2], w3v[2];
    #pragma unroll
    for (int nt = 0; nt < 2; ++nt) {
        int j = wave * 32 + nt * 16 + (lane & 15);
        b2v[nt] = b2[j];
        w3v[nt] = W3[j];
        #pragma unroll
        for (int ks = 0; ks < 4; ++ks)
            bw[nt][ks] = *(const short8*)((const char*)W2T + j * 256 + ks * 64 + (lane >> 4) * 16);
    }

    int ntiles = (E + 31) / 32;
    for (int tile = blockIdx.x; tile < ntiles; tile += gridDim.x) {
        int e0 = tile * 32;
        // phase 1: gather + layer-1 finish + silu -> LDS
        for (int ei = esub; ei < 32; ei += 2) {
            int e = e0 + ei;
            if (e < E) {
                int row = eidx[e], col = eidx[E + e];
                float a = bf2f(AB[(size_t)row * 256 + ch]);
                float b = bf2f(AB[(size_t)col * 256 + 128 + ch]);
                float pre = a + b + edge_attr[e] * w1c;
                float x1 = silu(pre);
                int byteoff = ei * 256 + ((ch * 2) ^ ((ei & 7) << 4));
                *(u16*)((char*)x1s + byteoff) = f2bf(x1);
                if (ch == 0) srow[ei] = row;
                if (ch < 3) scd[ei][ch] = coord_diff[(size_t)e * 3 + ch] * edge_mask[e];
            }
        }
        __syncthreads();

        // phase 2: x2 = silu(X1 @ W2 + b2); scale partials
        f32x4 acc[2][2] = {};
        #pragma unroll
        for (int ks = 0; ks < 4; ++ks) {
            short8 a[2];
            #pragma unroll
            for (int mt = 0; mt < 2; ++mt) {
                int row = mt * 16 + (lane & 15);
                int byteoff = row * 256 + (((ks * 64) + ((lane >> 4) * 16)) ^ ((row & 7) << 4));
                a[mt] = *(short8*)((char*)x1s + byteoff);
            }
            #pragma unroll
            for (int mt = 0; mt < 2; ++mt)
                #pragma unroll
                for (int nt = 0; nt < 2; ++nt)
                    acc[mt][nt] = __builtin_amdgcn_mfma_f32_16x16x32_bf16(a[mt], bw[nt][ks], acc[mt][nt], 0, 0, 0);
        }
        #pragma unroll
        for (int mt = 0; mt < 2; ++mt) {
            #pragma unroll
            for (int r = 0; r < 4; ++r) {
                float s = 0.f;
                #pragma unroll
                for (int nt = 0; nt < 2; ++nt) {
                    float v = acc[mt][nt][r] + b2v[nt];
                    s += silu(v) * w3v[nt];
                }
                s += __shfl_xor(s, 1);
                s += __shfl_xor(s, 2);
                s += __shfl_xor(s, 4);
                s += __shfl_xor(s, 8);
                if ((lane & 15) == 0) sp[wave][mt * 16 + (lane >> 4) * 4 + r] = s;
            }
        }
        __syncthreads();

        // phase 3: scale -> 3 atomic adds per edge
        if (tid < 32 && e0 + tid < E) {
            float sc = sp[0][tid] + sp[1][tid] + sp[2][tid] + sp[3][tid];
            int r = srow[tid];
            atomicAdd(&agg[r * 3 + 0], scd[tid][0] * sc);
            atomicAdd(&agg[r * 3 + 1], scd[tid][1] * sc);
            atomicAdd(&agg[r * 3 + 2], scd[tid][2] * sc);
        }
        __syncthreads();
    }
}

// ---------------- kernel 3: coord update ----------------
__global__ void finalize(const float* __restrict__ coord, const float* __restrict__ agg,
                         const float* __restrict__ node_mask, float* __restrict__ out, int n3) {
    int i = blockIdx.x * blockDim.x + threadIdx.x;
    if (i < n3) {
        int n = i / 3;
        out[i] = (coord[i] + agg[i] * NORM_INV) * node_mask[n];
    }
}

extern "C" void kernel_launch(void* const* d_in, const int* in_sizes, int n_in,
                              void* d_out, int out_size, void* d_ws, size_t ws_size,
                              hipStream_t stream) {
    const float* h          = (const float*)d_in[0];
    const float* coord      = (const float*)d_in[1];
    const int*   eidx       = (const int*)d_in[2];
    const float* coord_diff = (const float*)d_in[3];
    const float* edge_attr  = (const float*)d_in[4];
    const float* node_mask  = (const float*)d_in[5];
    const float* edge_mask  = (const float*)d_in[6];
    const float* W1         = (const float*)d_in[7];
    const float* b1         = (const float*)d_in[8];
    const float* W2         = (const float*)d_in[9];
    const float* b2         = (const float*)d_in[10];
    const float* W3         = (const float*)d_in[11];

    int N = in_sizes[0] / 128;   // 50000
    int E = in_sizes[2] / 2;     // 800000

    char* ws = (char*)d_ws;
    size_t off = 0;
    u16* AB    = (u16*)(ws + off); off += (size_t)N * 256 * sizeof(u16); off = (off + 255) & ~(size_t)255;
    u16* W1abT = (u16*)(ws + off); off += 256 * 128 * sizeof(u16);
    u16* W2T   = (u16*)(ws + off); off += 128 * 128 * sizeof(u16);
    float* agg = (float*)(ws + off); off += (size_t)N * 3 * sizeof(float);

    hipMemsetAsync(agg, 0, (size_t)N * 3 * sizeof(float), stream);
    hipLaunchKernelGGL(prep_weights, dim3(192), dim3(256), 0, stream, W1, W2, W1abT, W2T);
    hipLaunchKernelGGL(ab_kernel, dim3((N + 31) / 32), dim3(256), 0, stream, h, b1, W1abT, AB, N);
    hipLaunchKernelGGL(edge_kernel, dim3(2048), dim3(256), 0, stream,
                       AB, W2T, eidx, coord_diff, edge_attr, edge_mask, W1, b2, W3, agg, E);
    int n3 = N * 3;
    hipLaunchKernelGGL(finalize, dim3((n3 + 255) / 256), dim3(256), 0, stream,
                       coord, agg, node_mask, (float*)d_out, n3);
}

// Round 2
// 237.674 us; speedup vs baseline: 2.1614x; 2.1614x over previous
//
#include <hip/hip_runtime.h>
#include <hip/hip_bf16.h>

typedef __attribute__((ext_vector_type(8))) short short8;
typedef __attribute__((ext_vector_type(4))) float f32x4;
typedef unsigned short u16;
typedef unsigned int u32;

#define NORM_INV (1.0f / 100.0f)

__device__ __forceinline__ float silu(float x) {
    return x / (1.0f + __expf(-x));
}

__device__ __forceinline__ u16 f2bf(float x) {
    union { float f; u32 u; } v; v.f = x;
    u32 r = v.u + 0x7fff + ((v.u >> 16) & 1);   // RNE
    return (u16)(r >> 16);
}

__device__ __forceinline__ float bf2f(u16 b) {
    union { u32 u; float f; } v; v.u = ((u32)b) << 16;
    return v.f;
}

// ---------------- kernel 0: weight transposes (tiny) ----------------
__global__ void prep_weights(const float* __restrict__ W1, const float* __restrict__ W2,
                             u16* __restrict__ W1abT, u16* __restrict__ W2T) {
    int idx = blockIdx.x * blockDim.x + threadIdx.x;
    if (idx < 256 * 128) {
        int j = idx >> 7, k = idx & 127;
        float v = (j < 128) ? W1[k * 128 + j] : W1[(128 + k) * 128 + (j - 128)];
        W1abT[j * 128 + k] = f2bf(v);
    } else if (idx < 256 * 128 + 128 * 128) {
        int t = idx - 256 * 128;
        int n = t >> 7, k = t & 127;
        W2T[n * 128 + k] = f2bf(W2[k * 128 + n]);
    }
}

// ---------------- kernel 1: AB[node][256] = [h@W1a + b1 | h@W1b] ----------------
__global__ __launch_bounds__(256) void ab_kernel(const float* __restrict__ h,
        const float* __restrict__ b1, const u16* __restrict__ W1abT,
        u16* __restrict__ AB, int N) {
    __shared__ u16 hs[32 * 128];     // 32 nodes x 128 k, bf16, XOR-swizzled
    int tid = threadIdx.x;
    int n0 = blockIdx.x * 32;
    int lane = tid & 63, wave = tid >> 6;

    // stage h tile -> bf16 LDS (swizzle: byte ^= (row&7)<<4)
    #pragma unroll
    for (int it = 0; it < 8; ++it) {
        int item = it * 256 + tid;          // 2048 items, 2 k each
        int m = item >> 6;
        int k = (item & 63) * 2;
        float2 hv = make_float2(0.f, 0.f);
        if (n0 + m < N) hv = *(const float2*)(h + (size_t)(n0 + m) * 128 + k);
        u32 pk = (u32)f2bf(hv.x) | ((u32)f2bf(hv.y) << 16);
        int byteoff = m * 256 + ((k * 2) ^ ((m & 7) << 4));
        *(u32*)((char*)hs + byteoff) = pk;
    }

    // W1abT B-fragments, held in registers: wave covers cols wave*64 .. +63
    short8 bw[4][4];
    #pragma unroll
    for (int nt = 0; nt < 4; ++nt) {
        int j = wave * 64 + nt * 16 + (lane & 15);
        #pragma unroll
        for (int ks = 0; ks < 4; ++ks)
            bw[nt][ks] = *(const short8*)((const char*)W1abT + j * 256 + ks * 64 + (lane >> 4) * 16);
    }
    __syncthreads();

    f32x4 acc[2][4] = {};
    #pragma unroll
    for (int ks = 0; ks < 4; ++ks) {
        short8 a[2];
        #pragma unroll
        for (int mt = 0; mt < 2; ++mt) {
            int row = mt * 16 + (lane & 15);
            int byteoff = row * 256 + (((ks * 64) + ((lane >> 4) * 16)) ^ ((row & 7) << 4));
            a[mt] = *(short8*)((char*)hs + byteoff);
        }
        #pragma unroll
        for (int mt = 0; mt < 2; ++mt)
            #pragma unroll
            for (int nt = 0; nt < 4; ++nt)
                acc[mt][nt] = __builtin_amdgcn_mfma_f32_16x16x32_bf16(a[mt], bw[nt][ks], acc[mt][nt], 0, 0, 0);
    }

    // epilogue: + b1 on A-half, store bf16
    #pragma unroll
    for (int mt = 0; mt < 2; ++mt) {
        #pragma unroll
        for (int nt = 0; nt < 4; ++nt) {
            int j = wave * 64 + nt * 16 + (lane & 15);
            float bias = (j < 128) ? b1[j] : 0.f;
            #pragma unroll
            for (int r = 0; r < 4; ++r) {
                int node = n0 + mt * 16 + (lane >> 4) * 4 + r;
                if (node < N) AB[(size_t)node * 256 + j] = f2bf(acc[mt][nt][r] + bias);
            }
        }
    }
}

// ---------------- kernel 2: per-edge MLP + scatter (64-edge tiles) ----------------
__global__ __launch_bounds__(256) void edge_kernel(
        const u16* __restrict__ AB, const u16* __restrict__ W2T,
        const int* __restrict__ eidx, const float* __restrict__ coord_diff,
        const float* __restrict__ edge_attr, const float* __restrict__ edge_mask,
        const float* __restrict__ W1, const float* __restrict__ b2,
        const float* __restrict__ W3, float* __restrict__ agg, int E) {
    __shared__ u16 x1s[64 * 128];     // 64 edges x 128 ch, bf16, swizzled (16 KB)
    __shared__ float sp[4][64];
    __shared__ int srow[64];
    __shared__ int scol[64];
    __shared__ float sea[64];
    __shared__ float scd[192];        // coord_diff * edge_mask, flat [64][3]
    __shared__ float sw1c[128];

    int tid = threadIdx.x;
    int lane = tid & 63, wave = tid >> 6;

    if (tid < 128) sw1c[tid] = W1[256 * 128 + tid];   // last row of W1

    // W2 B-fragments in registers: wave covers out cols wave*32 .. +31
    short8 bw[2][4];
    float b2v[2], w3v[2];
    #pragma unroll
    for (int nt = 0; nt < 2; ++nt) {
        int j = wave * 32 + nt * 16 + (lane & 15);
        b2v[nt] = b2[j];
        w3v[nt] = W3[j];
        #pragma unroll
        for (int ks = 0; ks < 4; ++ks)
            bw[nt][ks] = *(const short8*)((const char*)W2T + j * 256 + ks * 64 + (lane >> 4) * 16);
    }
    __syncthreads();

    int ntiles = (E + 63) >> 6;
    for (int tile = blockIdx.x; tile < ntiles; tile += gridDim.x) {
        int e0 = tile * 64;

        // phase 0: stage per-edge metadata (coalesced)
        if (tid < 64) {
            int e = e0 + tid;
            bool v = e < E;
            srow[tid] = v ? eidx[e] : 0;
            scol[tid] = v ? eidx[E + e] : 0;
            sea[tid]  = v ? edge_attr[e] : 0.f;
        } else {
            int idx = tid - 64;               // 0..191
            int e = e0 + idx / 3;
            scd[idx] = (e < E) ? coord_diff[(size_t)e0 * 3 + idx] * edge_mask[e] : 0.f;
        }
        __syncthreads();

        // phase 1: vectorized gather (16B loads) + layer-1 finish + silu -> LDS
        short8 va[4], vb[4];
        #pragma unroll
        for (int it = 0; it < 4; ++it) {
            int i = it * 256 + tid;           // 1024 items: e = i>>4, g = i&15
            int e = i >> 4, g = i & 15;
            va[it] = *(const short8*)(AB + (size_t)srow[e] * 256 + g * 8);
            vb[it] = *(const short8*)(AB + (size_t)scol[e] * 256 + 128 + g * 8);
        }
        #pragma unroll
        for (int it = 0; it < 4; ++it) {
            int i = it * 256 + tid;
            int e = i >> 4, g = i & 15;
            float ea = sea[e];
            u32 pk[4];
            #pragma unroll
            for (int jp = 0; jp < 4; ++jp) {
                float x0 = bf2f((u16)va[it][2 * jp])     + bf2f((u16)vb[it][2 * jp])     + ea * sw1c[g * 8 + 2 * jp];
                float x1 = bf2f((u16)va[it][2 * jp + 1]) + bf2f((u16)vb[it][2 * jp + 1]) + ea * sw1c[g * 8 + 2 * jp + 1];
                pk[jp] = (u32)f2bf(silu(x0)) | ((u32)f2bf(silu(x1)) << 16);
            }
            int byteoff = e * 256 + ((g * 16) ^ ((e & 7) << 4));
            *(uint4*)((char*)x1s + byteoff) = make_uint4(pk[0], pk[1], pk[2], pk[3]);
        }
        __syncthreads();

        // phase 2: x2 = silu(X1 @ W2 + b2); per-wave partial dot with W3
        f32x4 acc[4][2] = {};
        #pragma unroll
        for (int ks = 0; ks < 4; ++ks) {
            short8 a[4];
            #pragma unroll
            for (int mt = 0; mt < 4; ++mt) {
                int row = mt * 16 + (lane & 15);
                int byteoff = row * 256 + (((ks * 64) + ((lane >> 4) * 16)) ^ ((row & 7) << 4));
                a[mt] = *(short8*)((char*)x1s + byteoff);
            }
            #pragma unroll
            for (int mt = 0; mt < 4; ++mt)
                #pragma unroll
                for (int nt = 0; nt < 2; ++nt)
                    acc[mt][nt] = __builtin_amdgcn_mfma_f32_16x16x32_bf16(a[mt], bw[nt][ks], acc[mt][nt], 0, 0, 0);
        }
        #pragma unroll
        for (int mt = 0; mt < 4; ++mt) {
            #pragma unroll
            for (int r = 0; r < 4; ++r) {
                float s = 0.f;
                #pragma unroll
                for (int nt = 0; nt < 2; ++nt) {
                    float v = acc[mt][nt][r] + b2v[nt];
                    s += silu(v) * w3v[nt];
                }
                s += __shfl_xor(s, 1);
                s += __shfl_xor(s, 2);
                s += __shfl_xor(s, 4);
                s += __shfl_xor(s, 8);
                if ((lane & 15) == 0) sp[wave][mt * 16 + (lane >> 4) * 4 + r] = s;
            }
        }
        __syncthreads();

        // phase 3: scale -> 3 atomic adds per edge (192 threads, 3 per edge)
        if (tid < 192) {
            int el = tid / 3;
            if (e0 + el < E) {
                float sc = sp[0][el] + sp[1][el] + sp[2][el] + sp[3][el];
                atomicAdd(&agg[srow[el] * 3 + (tid - el * 3)], scd[tid] * sc);
            }
        }
        __syncthreads();
    }
}

// ---------------- kernel 3: coord update ----------------
__global__ void finalize(const float* __restrict__ coord, const float* __restrict__ agg,
                         const float* __restrict__ node_mask, float* __restrict__ out, int n3) {
    int i = blockIdx.x * blockDim.x + threadIdx.x;
    if (i < n3) {
        int n = i / 3;
        out[i] = (coord[i] + agg[i] * NORM_INV) * node_mask[n];
    }
}

extern "C" void kernel_launch(void* const* d_in, const int* in_sizes, int n_in,
                              void* d_out, int out_size, void* d_ws, size_t ws_size,
                              hipStream_t stream) {
    const float* h          = (const float*)d_in[0];
    const float* coord      = (const float*)d_in[1];
    const int*   eidx       = (const int*)d_in[2];
    const float* coord_diff = (const float*)d_in[3];
    const float* edge_attr  = (const float*)d_in[4];
    const float* node_mask  = (const float*)d_in[5];
    const float* edge_mask  = (const float*)d_in[6];
    const float* W1         = (const float*)d_in[7];
    const float* b1         = (const float*)d_in[8];
    const float* W2         = (const float*)d_in[9];
    const float* b2         = (const float*)d_in[10];
    const float* W3         = (const float*)d_in[11];

    int N = in_sizes[0] / 128;   // 50000
    int E = in_sizes[2] / 2;     // 800000

    char* ws = (char*)d_ws;
    size_t off = 0;
    u16* AB    = (u16*)(ws + off); off += (size_t)N * 256 * sizeof(u16); off = (off + 255) & ~(size_t)255;
    u16* W1abT = (u16*)(ws + off); off += 256 * 128 * sizeof(u16);
    u16* W2T   = (u16*)(ws + off); off += 128 * 128 * sizeof(u16);
    float* agg = (float*)(ws + off); off += (size_t)N * 3 * sizeof(float);

    hipMemsetAsync(agg, 0, (size_t)N * 3 * sizeof(float), stream);
    hipLaunchKernelGGL(prep_weights, dim3(192), dim3(256), 0, stream, W1, W2, W1abT, W2T);
    hipLaunchKernelGGL(ab_kernel, dim3((N + 31) / 32), dim3(256), 0, stream, h, b1, W1abT, AB, N);
    hipLaunchKernelGGL(edge_kernel, dim3(2048), dim3(256), 0, stream,
                       AB, W2T, eidx, coord_diff, edge_attr, edge_mask, W1, b2, W3, agg, E);
    int n3 = N * 3;
    hipLaunchKernelGGL(finalize, dim3((n3 + 255) / 256), dim3(256), 0, stream,
                       coord, agg, node_mask, (float*)d_out, n3);
}

// Round 3
// 200.365 us; speedup vs baseline: 2.5638x; 1.1862x over previous
//
#include <hip/hip_runtime.h>
#include <hip/hip_bf16.h>

typedef __attribute__((ext_vector_type(8))) short short8;
typedef __attribute__((ext_vector_type(4))) float f32x4;
typedef unsigned short u16;
typedef unsigned int u32;

#define NORM_INV (1.0f / 100.0f)

__device__ __forceinline__ float silu(float x) {
    // x * 1/(1+exp(-x)); v_rcp_f32 is plenty accurate for our tolerance
    return x * __builtin_amdgcn_rcpf(1.0f + __expf(-x));
}

__device__ __forceinline__ u16 f2bf(float x) {
    union { float f; u32 u; } v; v.f = x;
    u32 r = v.u + 0x7fff + ((v.u >> 16) & 1);   // RNE
    return (u16)(r >> 16);
}

__device__ __forceinline__ float bf2f(u16 b) {
    union { u32 u; float f; } v; v.u = ((u32)b) << 16;
    return v.f;
}

// ---------------- kernel 0: weight transposes (tiny) ----------------
__global__ void prep_weights(const float* __restrict__ W1, const float* __restrict__ W2,
                             u16* __restrict__ W1abT, u16* __restrict__ W2T) {
    int idx = blockIdx.x * blockDim.x + threadIdx.x;
    if (idx < 256 * 128) {
        int j = idx >> 7, k = idx & 127;
        float v = (j < 128) ? W1[k * 128 + j] : W1[(128 + k) * 128 + (j - 128)];
        W1abT[j * 128 + k] = f2bf(v);
    } else if (idx < 256 * 128 + 128 * 128) {
        int t = idx - 256 * 128;
        int n = t >> 7, k = t & 127;
        W2T[n * 128 + k] = f2bf(W2[k * 128 + n]);
    }
}

// ---------------- kernel 1: AB[node][256] = [h@W1a + b1 | h@W1b] ----------------
__global__ __launch_bounds__(256) void ab_kernel(const float* __restrict__ h,
        const float* __restrict__ b1, const u16* __restrict__ W1abT,
        u16* __restrict__ AB, int N) {
    __shared__ u16 hs[32 * 128];     // 32 nodes x 128 k, bf16, XOR-swizzled
    int tid = threadIdx.x;
    int n0 = blockIdx.x * 32;
    int lane = tid & 63, wave = tid >> 6;

    #pragma unroll
    for (int it = 0; it < 8; ++it) {
        int item = it * 256 + tid;          // 2048 items, 2 k each
        int m = item >> 6;
        int k = (item & 63) * 2;
        float2 hv = make_float2(0.f, 0.f);
        if (n0 + m < N) hv = *(const float2*)(h + (size_t)(n0 + m) * 128 + k);
        u32 pk = (u32)f2bf(hv.x) | ((u32)f2bf(hv.y) << 16);
        int byteoff = m * 256 + ((k * 2) ^ ((m & 7) << 4));
        *(u32*)((char*)hs + byteoff) = pk;
    }

    short8 bw[4][4];
    #pragma unroll
    for (int nt = 0; nt < 4; ++nt) {
        int j = wave * 64 + nt * 16 + (lane & 15);
        #pragma unroll
        for (int ks = 0; ks < 4; ++ks)
            bw[nt][ks] = *(const short8*)((const char*)W1abT + j * 256 + ks * 64 + (lane >> 4) * 16);
    }
    __syncthreads();

    f32x4 acc[2][4] = {};
    #pragma unroll
    for (int ks = 0; ks < 4; ++ks) {
        short8 a[2];
        #pragma unroll
        for (int mt = 0; mt < 2; ++mt) {
            int row = mt * 16 + (lane & 15);
            int byteoff = row * 256 + (((ks * 64) + ((lane >> 4) * 16)) ^ ((row & 7) << 4));
            a[mt] = *(short8*)((char*)hs + byteoff);
        }
        #pragma unroll
        for (int mt = 0; mt < 2; ++mt)
            #pragma unroll
            for (int nt = 0; nt < 4; ++nt)
                acc[mt][nt] = __builtin_amdgcn_mfma_f32_16x16x32_bf16(a[mt], bw[nt][ks], acc[mt][nt], 0, 0, 0);
    }

    #pragma unroll
    for (int mt = 0; mt < 2; ++mt) {
        #pragma unroll
        for (int nt = 0; nt < 4; ++nt) {
            int j = wave * 64 + nt * 16 + (lane & 15);
            float bias = (j < 128) ? b1[j] : 0.f;
            #pragma unroll
            for (int r = 0; r < 4; ++r) {
                int node = n0 + mt * 16 + (lane >> 4) * 4 + r;
                if (node < N) AB[(size_t)node * 256 + j] = f2bf(acc[mt][nt][r] + bias);
            }
        }
    }
}

// ---------------- kernel 2: per-edge MLP + scatter, software-pipelined ----------------
__global__ __launch_bounds__(256) void edge_kernel(
        const u16* __restrict__ AB, const u16* __restrict__ W2T,
        const int* __restrict__ eidx, const float* __restrict__ coord_diff,
        const float* __restrict__ edge_attr, const float* __restrict__ edge_mask,
        const float* __restrict__ W1, const float* __restrict__ b2,
        const float* __restrict__ W3, float* __restrict__ agg, int E) {
    __shared__ u16 x1s[64 * 128];     // 64 edges x 128 ch, bf16, swizzled (16 KB)
    __shared__ float sp[2][4][64];    // per-wave partial sums, double-buffered
    __shared__ int srow[2][64];
    __shared__ float sw1c[128];

    const int tid = threadIdx.x;
    const int lane = tid & 63, wave = tid >> 6;
    const int g = tid & 15;           // channel-group (8 ch per group)
    const int esub4 = tid >> 4;       // 0..15: sub-edge within 16-edge stripe

    if (tid < 128) sw1c[tid] = W1[256 * 128 + tid];   // last row of W1

    // W2 B-fragments in registers: wave covers out cols wave*32 .. +31
    short8 bw[2][4];
    float b2v[2], w3v[2];
    #pragma unroll
    for (int nt = 0; nt < 2; ++nt) {
        int j = wave * 32 + nt * 16 + (lane & 15);
        b2v[nt] = b2[j];
        w3v[nt] = W3[j];
        #pragma unroll
        for (int ks = 0; ks < 4; ++ks)
            bw[nt][ks] = *(const short8*)((const char*)W2T + j * 256 + ks * 64 + (lane >> 4) * 16);
    }
    __syncthreads();   // sw1c ready

    const int ntiles = (E + 63) >> 6;
    int tile = blockIdx.x;
    if (tile >= ntiles) return;

    // ---- prologue: meta + gathers for first tile (latency exposed once)
    int rowc[4];
    float eac[4];
    short8 va[4], vb[4];
    {
        int colc[4];
        #pragma unroll
        for (int it = 0; it < 4; ++it) {
            int e = tile * 64 + it * 16 + esub4;
            int ec = e < E ? e : E - 1;
            rowc[it] = eidx[ec]; colc[it] = eidx[E + ec]; eac[it] = edge_attr[ec];
        }
        #pragma unroll
        for (int it = 0; it < 4; ++it) {
            va[it] = *(const short8*)(AB + (size_t)rowc[it] * 256 + g * 8);
            vb[it] = *(const short8*)(AB + (size_t)colc[it] * 256 + 128 + g * 8);
        }
    }
    float cdmc = 0.f;
    if (tid < 192) {
        int e = tile * 64 + tid / 3;
        if (e < E) cdmc = coord_diff[(size_t)tile * 192 + tid] * edge_mask[e];
    }

    int buf = 0;
    while (true) {
        int next = tile + gridDim.x;
        bool hn = next < ntiles;

        // step 1: issue next tile's meta loads (broadcast-coalesced)
        int rown[4], coln[4];
        float ean[4], cdmn = 0.f;
        if (hn) {
            #pragma unroll
            for (int it = 0; it < 4; ++it) {
                int e = next * 64 + it * 16 + esub4;
                int ec = e < E ? e : E - 1;
                rown[it] = eidx[ec]; coln[it] = eidx[E + ec]; ean[it] = edge_attr[ec];
            }
            if (tid < 192) {
                int e = next * 64 + tid / 3;
                if (e < E) cdmn = coord_diff[(size_t)next * 192 + tid] * edge_mask[e];
            }
        }

        // step 2: convert current gathered regs -> x1 LDS tile (+ srow)
        #pragma unroll
        for (int it = 0; it < 4; ++it) {
            int e = it * 16 + esub4;
            float ea = eac[it];
            u32 pk[4];
            #pragma unroll
            for (int jp = 0; jp < 4; ++jp) {
                float x0 = bf2f((u16)va[it][2 * jp])     + bf2f((u16)vb[it][2 * jp])     + ea * sw1c[g * 8 + 2 * jp];
                float x1 = bf2f((u16)va[it][2 * jp + 1]) + bf2f((u16)vb[it][2 * jp + 1]) + ea * sw1c[g * 8 + 2 * jp + 1];
                pk[jp] = (u32)f2bf(silu(x0)) | ((u32)f2bf(silu(x1)) << 16);
            }
            int byteoff = e * 256 + ((g * 16) ^ ((e & 7) << 4));
            *(uint4*)((char*)x1s + byteoff) = make_uint4(pk[0], pk[1], pk[2], pk[3]);
            if (g == 0) srow[buf][e] = rowc[it];
        }
        __syncthreads();   // barrier A: x1s + srow[buf] ready

        // step 4: issue next tile's AB gathers (hide under MFMA below)
        short8 va2[4], vb2[4];
        if (hn) {
            #pragma unroll
            for (int it = 0; it < 4; ++it) {
                va2[it] = *(const short8*)(AB + (size_t)rown[it] * 256 + g * 8);
                vb2[it] = *(const short8*)(AB + (size_t)coln[it] * 256 + 128 + g * 8);
            }
        }

        // step 5: x2 = silu(X1 @ W2 + b2); per-wave partial dot with W3
        f32x4 acc[4][2] = {};
        #pragma unroll
        for (int ks = 0; ks < 4; ++ks) {
            short8 a[4];
            #pragma unroll
            for (int mt = 0; mt < 4; ++mt) {
                int row = mt * 16 + (lane & 15);
                int byteoff = row * 256 + (((ks * 64) + ((lane >> 4) * 16)) ^ ((row & 7) << 4));
                a[mt] = *(short8*)((char*)x1s + byteoff);
            }
            #pragma unroll
            for (int mt = 0; mt < 4; ++mt)
                #pragma unroll
                for (int nt = 0; nt < 2; ++nt)
                    acc[mt][nt] = __builtin_amdgcn_mfma_f32_16x16x32_bf16(a[mt], bw[nt][ks], acc[mt][nt], 0, 0, 0);
        }
        #pragma unroll
        for (int mt = 0; mt < 4; ++mt) {
            #pragma unroll
            for (int r = 0; r < 4; ++r) {
                float s = 0.f;
                #pragma unroll
                for (int nt = 0; nt < 2; ++nt) {
                    float v = acc[mt][nt][r] + b2v[nt];
                    s += silu(v) * w3v[nt];
                }
                s += __shfl_xor(s, 1);
                s += __shfl_xor(s, 2);
                s += __shfl_xor(s, 4);
                s += __shfl_xor(s, 8);
                if ((lane & 15) == 0) sp[buf][wave][mt * 16 + (lane >> 4) * 4 + r] = s;
            }
        }
        __syncthreads();   // barrier B: sp[buf] ready

        // step 7: scale -> 3 atomic adds per edge
        if (tid < 192) {
            int el = tid / 3;
            if (tile * 64 + el < E) {
                float sc = sp[buf][0][el] + sp[buf][1][el] + sp[buf][2][el] + sp[buf][3][el];
                atomicAdd(&agg[srow[buf][el] * 3 + (tid - el * 3)], cdmc * sc);
            }
        }

        if (!hn) break;
        // step 8: rotate pipeline registers
        #pragma unroll
        for (int it = 0; it < 4; ++it) {
            va[it] = va2[it]; vb[it] = vb2[it];
            rowc[it] = rown[it]; eac[it] = ean[it];
        }
        cdmc = cdmn;
        buf ^= 1;
        tile = next;
    }
}

// ---------------- kernel 3: coord update ----------------
__global__ void finalize(const float* __restrict__ coord, const float* __restrict__ agg,
                         const float* __restrict__ node_mask, float* __restrict__ out, int n3) {
    int i = blockIdx.x * blockDim.x + threadIdx.x;
    if (i < n3) {
        int n = i / 3;
        out[i] = (coord[i] + agg[i] * NORM_INV) * node_mask[n];
    }
}

extern "C" void kernel_launch(void* const* d_in, const int* in_sizes, int n_in,
                              void* d_out, int out_size, void* d_ws, size_t ws_size,
                              hipStream_t stream) {
    const float* h          = (const float*)d_in[0];
    const float* coord      = (const float*)d_in[1];
    const int*   eidx       = (const int*)d_in[2];
    const float* coord_diff = (const float*)d_in[3];
    const float* edge_attr  = (const float*)d_in[4];
    const float* node_mask  = (const float*)d_in[5];
    const float* edge_mask  = (const float*)d_in[6];
    const float* W1         = (const float*)d_in[7];
    const float* b1         = (const float*)d_in[8];
    const float* W2         = (const float*)d_in[9];
    const float* b2         = (const float*)d_in[10];
    const float* W3         = (const float*)d_in[11];

    int N = in_sizes[0] / 128;   // 50000
    int E = in_sizes[2] / 2;     // 800000

    char* ws = (char*)d_ws;
    size_t off = 0;
    u16* AB    = (u16*)(ws + off); off += (size_t)N * 256 * sizeof(u16); off = (off + 255) & ~(size_t)255;
    u16* W1abT = (u16*)(ws + off); off += 256 * 128 * sizeof(u16);
    u16* W2T   = (u16*)(ws + off); off += 128 * 128 * sizeof(u16);
    float* agg = (float*)(ws + off); off += (size_t)N * 3 * sizeof(float);

    hipMemsetAsync(agg, 0, (size_t)N * 3 * sizeof(float), stream);
    hipLaunchKernelGGL(prep_weights, dim3(192), dim3(256), 0, stream, W1, W2, W1abT, W2T);
    hipLaunchKernelGGL(ab_kernel, dim3((N + 31) / 32), dim3(256), 0, stream, h, b1, W1abT, AB, N);
    hipLaunchKernelGGL(edge_kernel, dim3(2048), dim3(256), 0, stream,
                       AB, W2T, eidx, coord_diff, edge_attr, edge_mask, W1, b2, W3, agg, E);
    int n3 = N * 3;
    hipLaunchKernelGGL(finalize, dim3((n3 + 255) / 256), dim3(256), 0, stream,
                       coord, agg, node_mask, (float*)d_out, n3);
}

// Round 4
// 172.876 us; speedup vs baseline: 2.9715x; 1.1590x over previous
//
#include <hip/hip_runtime.h>
#include <hip/hip_bf16.h>

typedef __attribute__((ext_vector_type(8))) short short8;
typedef __attribute__((ext_vector_type(4))) float f32x4;
typedef unsigned short u16;
typedef unsigned int u32;

#define NORM_INV (1.0f / 100.0f)

__device__ __forceinline__ float silu(float x) {
    return x * __builtin_amdgcn_rcpf(1.0f + __expf(-x));
}

__device__ __forceinline__ u16 f2bf(float x) {
    union { float f; u32 u; } v; v.f = x;
    u32 r = v.u + 0x7fff + ((v.u >> 16) & 1);   // RNE
    return (u16)(r >> 16);
}

__device__ __forceinline__ float bflo(u32 u) {
    union { u32 u; float f; } v; v.u = u << 16; return v.f;
}
__device__ __forceinline__ float bfhi(u32 u) {
    union { u32 u; float f; } v; v.u = u & 0xffff0000u; return v.f;
}

// ---------------- kernel 0: weight transposes (tiny) ----------------
__global__ void prep_weights(const float* __restrict__ W1, const float* __restrict__ W2,
                             u16* __restrict__ W1abT, u16* __restrict__ W2T) {
    int idx = blockIdx.x * blockDim.x + threadIdx.x;
    if (idx < 256 * 128) {
        int j = idx >> 7, k = idx & 127;
        float v = (j < 128) ? W1[k * 128 + j] : W1[(128 + k) * 128 + (j - 128)];
        W1abT[j * 128 + k] = f2bf(v);
    } else if (idx < 256 * 128 + 128 * 128) {
        int t = idx - 256 * 128;
        int n = t >> 7, k = t & 127;
        W2T[n * 128 + k] = f2bf(W2[k * 128 + n]);
    }
}

// ---------------- kernel 1: AB[node][256] = [h@W1a + b1 | h@W1b] ----------------
__global__ __launch_bounds__(256) void ab_kernel(const float* __restrict__ h,
        const float* __restrict__ b1, const u16* __restrict__ W1abT,
        u16* __restrict__ AB, int N) {
    __shared__ u16 hs[32 * 128];     // 32 nodes x 128 k, bf16, XOR-swizzled
    int tid = threadIdx.x;
    int n0 = blockIdx.x * 32;
    int lane = tid & 63, wave = tid >> 6;

    #pragma unroll
    for (int it = 0; it < 8; ++it) {
        int item = it * 256 + tid;          // 2048 items, 2 k each
        int m = item >> 6;
        int k = (item & 63) * 2;
        float2 hv = make_float2(0.f, 0.f);
        if (n0 + m < N) hv = *(const float2*)(h + (size_t)(n0 + m) * 128 + k);
        u32 pk = (u32)f2bf(hv.x) | ((u32)f2bf(hv.y) << 16);
        int byteoff = m * 256 + ((k * 2) ^ ((m & 7) << 4));
        *(u32*)((char*)hs + byteoff) = pk;
    }

    short8 bw[4][4];
    #pragma unroll
    for (int nt = 0; nt < 4; ++nt) {
        int j = wave * 64 + nt * 16 + (lane & 15);
        #pragma unroll
        for (int ks = 0; ks < 4; ++ks)
            bw[nt][ks] = *(const short8*)((const char*)W1abT + j * 256 + ks * 64 + (lane >> 4) * 16);
    }
    __syncthreads();

    f32x4 acc[2][4] = {};
    #pragma unroll
    for (int ks = 0; ks < 4; ++ks) {
        short8 a[2];
        #pragma unroll
        for (int mt = 0; mt < 2; ++mt) {
            int row = mt * 16 + (lane & 15);
            int byteoff = row * 256 + (((ks * 64) + ((lane >> 4) * 16)) ^ ((row & 7) << 4));
            a[mt] = *(short8*)((char*)hs + byteoff);
        }
        #pragma unroll
        for (int mt = 0; mt < 2; ++mt)
            #pragma unroll
            for (int nt = 0; nt < 4; ++nt)
                acc[mt][nt] = __builtin_amdgcn_mfma_f32_16x16x32_bf16(a[mt], bw[nt][ks], acc[mt][nt], 0, 0, 0);
    }

    #pragma unroll
    for (int mt = 0; mt < 2; ++mt) {
        #pragma unroll
        for (int nt = 0; nt < 4; ++nt) {
            int j = wave * 64 + nt * 16 + (lane & 15);
            float bias = (j < 128) ? b1[j] : 0.f;
            #pragma unroll
            for (int r = 0; r < 4; ++r) {
                int node = n0 + mt * 16 + (lane >> 4) * 4 + r;
                if (node < N) AB[(size_t)node * 256 + j] = f2bf(acc[mt][nt][r] + bias);
            }
        }
    }
}

// ---------------- kernel 2: barrier-free wave-autonomous edge MLP + scatter ----------------
// Each wave owns 16-edge tiles. Gather produces MFMA A-fragments directly
// (lane l: edge=l&15, k-chunk=l>>4) -> no LDS transpose, no __syncthreads in loop.
__global__ __launch_bounds__(256) void edge_kernel(
        const u16* __restrict__ AB, const u16* __restrict__ W2T,
        const int* __restrict__ eidx, const float* __restrict__ coord_diff,
        const float* __restrict__ edge_attr, const float* __restrict__ edge_mask,
        const float* __restrict__ W1, const float* __restrict__ b2,
        const float* __restrict__ W3, float* __restrict__ agg, int E) {
    __shared__ u16 w2s[128 * 128];   // swizzled W2T copy (32 KB)
    __shared__ float ssc[4][16];     // per-wave scale scratch

    const int tid = threadIdx.x;
    const int lane = tid & 63;
    const int wv = tid >> 6;
    const int le = lane & 15;        // edge-sub (A rows) / col-sub (B cols)
    const int lg = lane >> 4;        // k-chunk group 0..3

    // stage W2T -> LDS, swizzled: byte ^= (row&7)<<4
    #pragma unroll
    for (int it = 0; it < 8; ++it) {
        int idx = it * 256 + tid;        // 2048 x 16B = 32 KB
        int j = idx >> 4, c16 = idx & 15;
        uint4 v = *(const uint4*)((const char*)W2T + idx * 16);
        *(uint4*)((char*)w2s + j * 256 + ((c16 * 16) ^ ((j & 7) << 4))) = v;
    }

    // per-lane constants
    float w1cv[4][8];                 // W1 edge_attr row, channels ks*32+lg*8+j
    #pragma unroll
    for (int ks = 0; ks < 4; ++ks) {
        float4 lo = *(const float4*)(W1 + 256 * 128 + ks * 32 + lg * 8);
        float4 hi = *(const float4*)(W1 + 256 * 128 + ks * 32 + lg * 8 + 4);
        w1cv[ks][0] = lo.x; w1cv[ks][1] = lo.y; w1cv[ks][2] = lo.z; w1cv[ks][3] = lo.w;
        w1cv[ks][4] = hi.x; w1cv[ks][5] = hi.y; w1cv[ks][6] = hi.z; w1cv[ks][7] = hi.w;
    }
    float b2v[8], w3v[8];
    #pragma unroll
    for (int nt = 0; nt < 8; ++nt) { b2v[nt] = b2[nt * 16 + le]; w3v[nt] = W3[nt * 16 + le]; }
    __syncthreads();                  // w2s ready (only barrier in the kernel)

    const int ntiles = (E + 15) >> 4;
    const int wpb = blockDim.x >> 6;
    const int nwaves = gridDim.x * wpb;
    int tile = blockIdx.x * wpb + wv;
    if (tile >= ntiles) return;

    // ---- prologue: meta(t0) + gather(t0)
    int e0 = tile << 4;
    int epc = min(e0 + le, E - 1);
    int rowc = eidx[epc];
    int colc = eidx[E + epc];
    float eac = edge_attr[epc];
    float eml = edge_mask[epc];
    float cdl = coord_diff[min(e0 * 3 + lane, E * 3 - 1)];

    uint4 va[4], vb[4];
    {
        const char* rp = (const char*)(AB + (size_t)rowc * 256);
        const char* cp = (const char*)(AB + (size_t)colc * 256 + 128);
        #pragma unroll
        for (int ks = 0; ks < 4; ++ks) {
            va[ks] = *(const uint4*)(rp + ks * 64 + lg * 16);
            vb[ks] = *(const uint4*)(cp + ks * 64 + lg * 16);
        }
    }

    while (true) {
        int next = tile + nwaves;
        bool hn = next < ntiles;
        int nb = hn ? next : tile;
        int ne0 = nb << 4;

        // issue meta(next) early (broadcast/coalesced; hides under convert)
        int nepc = min(ne0 + le, E - 1);
        int rown = eidx[nepc];
        int coln = eidx[E + nepc];
        float ean = edge_attr[nepc];
        float emn = edge_mask[nepc];
        float cdn = coord_diff[min(ne0 * 3 + lane, E * 3 - 1)];

        // convert current gathers -> A-fragments (layer-1 finish + silu, all in regs)
        short8 pa[4];
        #pragma unroll
        for (int ks = 0; ks < 4; ++ks) {
            union { u32 w[4]; short8 s; } u;
            #pragma unroll
            for (int jp = 0; jp < 4; ++jp) {
                u32 ua = ((const u32*)&va[ks])[jp];
                u32 ub = ((const u32*)&vb[ks])[jp];
                float p0 = bflo(ua) + bflo(ub) + eac * w1cv[ks][2 * jp];
                float p1 = bfhi(ua) + bfhi(ub) + eac * w1cv[ks][2 * jp + 1];
                float x0 = silu(p0), x1 = silu(p1);
                // truncating pack {bf16(x1),bf16(x0)} in 1 op
                u.w[jp] = __builtin_amdgcn_perm(__float_as_uint(x1), __float_as_uint(x0), 0x07060302);
            }
            pa[ks] = u.s;
        }

        // issue gather(next) into va/vb (latency hides under MFMA + epilogue)
        if (hn) {
            const char* rp = (const char*)(AB + (size_t)rown * 256);
            const char* cp = (const char*)(AB + (size_t)coln * 256 + 128);
            #pragma unroll
            for (int ks = 0; ks < 4; ++ks) {
                va[ks] = *(const uint4*)(rp + ks * 64 + lg * 16);
                vb[ks] = *(const uint4*)(cp + ks * 64 + lg * 16);
            }
        }

        // layer 2: x2 = X1 @ W2  (B-frags from swizzled LDS, 2-way conflicts only)
        f32x4 acc[8] = {};
        #pragma unroll
        for (int ks = 0; ks < 4; ++ks) {
            #pragma unroll
            for (int nt = 0; nt < 8; ++nt) {
                int row = nt * 16 + le;
                const short8 bwf = *(const short8*)((const char*)w2s +
                        row * 256 + (((ks * 64) + lg * 16) ^ ((le & 7) << 4)));
                acc[nt] = __builtin_amdgcn_mfma_f32_16x16x32_bf16(pa[ks], bwf, acc[nt], 0, 0, 0);
            }
        }

        // epilogue: scale[edge] = sum_c silu(x2+b2)*W3
        float s[4];
        #pragma unroll
        for (int r = 0; r < 4; ++r) {
            float t = 0.f;
            #pragma unroll
            for (int nt = 0; nt < 8; ++nt)
                t += silu(acc[nt][r] + b2v[nt]) * w3v[nt];
            t += __shfl_xor(t, 1);
            t += __shfl_xor(t, 2);
            t += __shfl_xor(t, 4);
            t += __shfl_xor(t, 8);
            s[r] = t;                 // edge lg*4+r, valid at le==0
        }
        if (le == 0) {
            f32x4 sv = { s[0], s[1], s[2], s[3] };
            *(f32x4*)&ssc[wv][lg * 4] = sv;   // same-wave LDS, lgkmcnt-ordered
        }

        // scatter: 3 atomics per edge (lanes 0..47)
        int els = (lane < 48) ? (lane / 3) : 0;
        int rA = __shfl(rowc, els);
        float emA = __shfl(eml, els);
        float sc = ssc[wv][els];
        if (lane < 48 && (e0 + els) < E)
            atomicAdd(&agg[rA * 3 + (lane - els * 3)], cdl * emA * sc);

        if (!hn) break;
        tile = next; e0 = ne0;
        rowc = rown; colc = coln; eac = ean; eml = emn; cdl = cdn;
    }
}

// ---------------- kernel 3: coord update ----------------
__global__ void finalize(const float* __restrict__ coord, const float* __restrict__ agg,
                         const float* __restrict__ node_mask, float* __restrict__ out, int n3) {
    int i = blockIdx.x * blockDim.x + threadIdx.x;
    if (i < n3) {
        int n = i / 3;
        out[i] = (coord[i] + agg[i] * NORM_INV) * node_mask[n];
    }
}

extern "C" void kernel_launch(void* const* d_in, const int* in_sizes, int n_in,
                              void* d_out, int out_size, void* d_ws, size_t ws_size,
                              hipStream_t stream) {
    const float* h          = (const float*)d_in[0];
    const float* coord      = (const float*)d_in[1];
    const int*   eidx       = (const int*)d_in[2];
    const float* coord_diff = (const float*)d_in[3];
    const float* edge_attr  = (const float*)d_in[4];
    const float* node_mask  = (const float*)d_in[5];
    const float* edge_mask  = (const float*)d_in[6];
    const float* W1         = (const float*)d_in[7];
    const float* b1         = (const float*)d_in[8];
    const float* W2         = (const float*)d_in[9];
    const float* b2         = (const float*)d_in[10];
    const float* W3         = (const float*)d_in[11];

    int N = in_sizes[0] / 128;   // 50000
    int E = in_sizes[2] / 2;     // 800000

    char* ws = (char*)d_ws;
    size_t off = 0;
    u16* AB    = (u16*)(ws + off); off += (size_t)N * 256 * sizeof(u16); off = (off + 255) & ~(size_t)255;
    u16* W1abT = (u16*)(ws + off); off += 256 * 128 * sizeof(u16);
    u16* W2T   = (u16*)(ws + off); off += 128 * 128 * sizeof(u16);
    float* agg = (float*)(ws + off); off += (size_t)N * 3 * sizeof(float);

    hipMemsetAsync(agg, 0, (size_t)N * 3 * sizeof(float), stream);
    hipLaunchKernelGGL(prep_weights, dim3(192), dim3(256), 0, stream, W1, W2, W1abT, W2T);
    hipLaunchKernelGGL(ab_kernel, dim3((N + 31) / 32), dim3(256), 0, stream, h, b1, W1abT, AB, N);
    hipLaunchKernelGGL(edge_kernel, dim3(1024), dim3(256), 0, stream,
                       AB, W2T, eidx, coord_diff, edge_attr, edge_mask, W1, b2, W3, agg, E);
    int n3 = N * 3;
    hipLaunchKernelGGL(finalize, dim3((n3 + 255) / 256), dim3(256), 0, stream,
                       coord, agg, node_mask, (float*)d_out, n3);
}